// Round 2
// baseline (897.016 us; speedup 1.0000x reference)
//
#include <hip/hip_runtime.h>
#include <math.h>

#define K_CODES 1024
#define D_DIM   256
#define B_SZ    32
#define HW      1024          // 32*32
#define N_ROWS  (B_SZ * HW)   // 32768
#define MROWS   32            // rows per block in main kernel
#define TK      128           // K-tile (codes per tile)
#define DC      64            // d-chunk for emb staging

// ---------- numpy-faithful pairwise sum of squares, one 128-elem block ----------
// Emulates numpy's npyv (AVX512, 16-lane) pairwise_sum path used by
// np.sum(x*x, axis=-1) for a contiguous 128-float block:
//   R(j,l) = sq[16j+l] + sq[64+16j+l]            (4 vector accumulators, 1 loop iter)
//   S(l)   = (R0+R1) + (R2+R3)
//   u(l)   = S(l) + S(l+8); v(m) = u(m) + u(m+4); res = (v0+v2) + (v1+v3)
__device__ __forceinline__ float pw_block128_sq(const float* a) {
    #pragma clang fp contract(off)
    float S[16];
    #pragma unroll
    for (int l = 0; l < 16; ++l) {
        float x0 = a[l],      x4 = a[64 + l];
        float x1 = a[16 + l], x5 = a[80 + l];
        float x2 = a[32 + l], x6 = a[96 + l];
        float x3 = a[48 + l], x7 = a[112 + l];
        float r0 = x0 * x0 + x4 * x4;
        float r1 = x1 * x1 + x5 * x5;
        float r2 = x2 * x2 + x6 * x6;
        float r3 = x3 * x3 + x7 * x7;
        S[l] = (r0 + r1) + (r2 + r3);
    }
    float u0 = S[0] + S[8],  u1 = S[1] + S[9],  u2 = S[2] + S[10], u3 = S[3] + S[11];
    float u4 = S[4] + S[12], u5 = S[5] + S[13], u6 = S[6] + S[14], u7 = S[7] + S[15];
    float v0 = u0 + u4, v1 = u1 + u5, v2 = u2 + u6, v3 = u3 + u7;
    return (v0 + v2) + (v1 + v3);
}

// numpy pairwise for n=256: split 128 + 128 (PW_BLOCKSIZE=128)
__device__ __forceinline__ float pw_sum256_sq(const float* a) {
    #pragma clang fp contract(off)
    float b0 = pw_block128_sq(a);
    float b1 = pw_block128_sq(a + 128);
    return b0 + b1;
}

// ---------------- K1: emb row norms (numpy-faithful) ----------------
__global__ void k_emb_norm(const float* __restrict__ emb, float* __restrict__ enorm) {
    int k = blockIdx.x * 256 + threadIdx.x;
    if (k < K_CODES) enorm[k] = pw_sum256_sq(emb + (size_t)k * D_DIM);
}

// ---------------- K2: main fused kernel ----------------
// scores s(n,k) = fl32( fl32(Z_n + E_k) - 2*fl32(dot_f64) ); argmin over k
// (first-index tie-break, matching np.argmin); then gather emb[best] ->
// z_q_out, loss partial, idx.
__global__ __launch_bounds__(256) void k_main(
    const float* __restrict__ z, const float* __restrict__ emb,
    const float* __restrict__ enorm,
    int* __restrict__ idx_ws, int* __restrict__ counts,
    float* __restrict__ loss_part,
    float* __restrict__ zq_out, float* __restrict__ idxf_out)
{
    __shared__ __align__(16) float zl[MROWS][D_DIM + 4];   // 32 x 260
    __shared__ __align__(16) float el[TK][DC + 4];         // 128 x 68
    __shared__ float zn_sh[MROWS];
    __shared__ float cv[MROWS][32];
    __shared__ int   ci[MROWS][32];
    __shared__ int   bestk_sh[MROWS];
    __shared__ float wsum[4];

    const int blk   = blockIdx.x;       // 0..1023
    const int batch = blk >> 5;         // 32 blocks per image
    const int p0    = (blk & 31) * MROWS;
    const float* zb = z + (size_t)batch * D_DIM * HW;
    const int tid   = threadIdx.x;

    // stage z tile: zl[p][d] = z[batch][d][p0+p]
    {
        int p = tid & 31;
        for (int d = tid >> 5; d < D_DIM; d += 8)
            zl[p][d] = zb[(size_t)d * HW + p0 + p];
    }
    __syncthreads();

    // numpy-faithful per-row ||z||^2
    if (tid < MROWS) zn_sh[tid] = pw_sum256_sq(&zl[tid][0]);
    // (visibility of zn_sh ensured by the __syncthreads inside the dc loop below)

    const int col_grp = tid & 31;   // 32 groups * 4 cols = 128
    const int row_grp = tid >> 5;   // 8 groups * 4 rows = 32
    const int r0 = row_grp * 4;

    float bestv[4] = {1e30f, 1e30f, 1e30f, 1e30f};
    int   besti[4] = {0, 0, 0, 0};

    for (int kt = 0; kt < K_CODES; kt += TK) {
        double acc[4][4] = {};
        for (int dc = 0; dc < D_DIM; dc += DC) {
            __syncthreads();   // protect el (prev chunk readers) / zl+zn first pass
            // stage e tile: el[c][dd] = emb[kt+c][dc+dd]
            {
                int dd4 = (tid & 15) * 4;   // 0..60
                for (int c = tid >> 4; c < TK; c += 16) {
                    float4 v = *reinterpret_cast<const float4*>(
                        emb + (size_t)(kt + c) * D_DIM + dc + dd4);
                    *reinterpret_cast<float4*>(&el[c][dd4]) = v;
                }
            }
            __syncthreads();
            #pragma unroll
            for (int dd = 0; dd < DC; dd += 4) {
                double ad[4][4], bd[4][4];
                #pragma unroll
                for (int r = 0; r < 4; ++r) {
                    float4 a4 = *reinterpret_cast<const float4*>(&zl[r0 + r][dc + dd]);
                    ad[r][0] = (double)a4.x; ad[r][1] = (double)a4.y;
                    ad[r][2] = (double)a4.z; ad[r][3] = (double)a4.w;
                }
                #pragma unroll
                for (int c = 0; c < 4; ++c) {
                    float4 b4 = *reinterpret_cast<const float4*>(&el[col_grp * 4 + c][dd]);
                    bd[c][0] = (double)b4.x; bd[c][1] = (double)b4.y;
                    bd[c][2] = (double)b4.z; bd[c][3] = (double)b4.w;
                }
                #pragma unroll
                for (int r = 0; r < 4; ++r)
                    #pragma unroll
                    for (int c = 0; c < 4; ++c)
                        acc[r][c] += ad[r][0] * bd[c][0] + ad[r][1] * bd[c][1]
                                   + ad[r][2] * bd[c][2] + ad[r][3] * bd[c][3];
            }
        }
        // fold into running argmin with numpy-faithful f32 quantization
        #pragma unroll
        for (int c = 0; c < 4; ++c) {
            int k = kt + col_grp * 4 + c;
            float en = enorm[k];
            #pragma unroll
            for (int r = 0; r < 4; ++r) {
                #pragma clang fp contract(off)
                float mf = (float)acc[r][c];      // RN(dot) in f32
                float t1 = zn_sh[r0 + r] + en;    // fl32(Z + E_k)
                float s  = t1 - 2.0f * mf;        // fl32(t1 - 2m)  (2m exact)
                if (s < bestv[r]) { bestv[r] = s; besti[r] = k; }
            }
        }
    }

    __syncthreads();
    #pragma unroll
    for (int r = 0; r < 4; ++r) { cv[r0 + r][col_grp] = bestv[r]; ci[r0 + r][col_grp] = besti[r]; }
    __syncthreads();

    if (tid < MROWS) {
        float bv = cv[tid][0]; int bi = ci[tid][0];
        for (int g = 1; g < 32; ++g) {
            float v = cv[tid][g]; int i = ci[tid][g];
            if (v < bv || (v == bv && i < bi)) { bv = v; bi = i; }
        }
        int n = batch * HW + p0 + tid;
        idx_ws[n] = bi;
        atomicAdd(&counts[bi], 1);
        idxf_out[n] = (float)bi;
        bestk_sh[tid] = bi;
    }
    __syncthreads();

    // gather phase: z_q_out + loss partial (z still in LDS)
    float lsum = 0.0f;
    {
        int p = tid & 31;
        const float* er = emb + (size_t)bestk_sh[p] * D_DIM;
        float* zqb = zq_out + (size_t)batch * D_DIM * HW + p0 + p;
        for (int d = tid >> 5; d < D_DIM; d += 8) {
            float e = er[d];
            float diff = e - zl[p][d];
            lsum += diff * diff;
            zqb[(size_t)d * HW] = e;
        }
    }
    #pragma unroll
    for (int off = 32; off > 0; off >>= 1) lsum += __shfl_down(lsum, off);
    if ((tid & 63) == 0) wsum[tid >> 6] = lsum;
    __syncthreads();
    if (tid == 0) loss_part[blk] = wsum[0] + wsum[1] + wsum[2] + wsum[3];
}

// ---------------- K3: scatter one-hot ones ----------------
__global__ void k_ones(const int* __restrict__ idx_ws, float* __restrict__ enc) {
    int n = blockIdx.x * 256 + threadIdx.x;
    enc[(size_t)n * K_CODES + idx_ws[n]] = 1.0f;
}

// ---------------- K4: finalize loss + perplexity ----------------
__global__ void k_final(const float* __restrict__ loss_part,
                        const int* __restrict__ counts,
                        float* __restrict__ out_loss, float* __restrict__ out_perp) {
    __shared__ float la[4], pa[4];
    int tid = threadIdx.x;
    float ls = 0.0f, ps = 0.0f;
    for (int i = tid; i < 1024; i += 256) {
        ls += loss_part[i];
        float em = (float)counts[i] * (1.0f / (float)N_ROWS);
        ps += em * logf(em + 1e-10f);
    }
    #pragma unroll
    for (int off = 32; off > 0; off >>= 1) {
        ls += __shfl_down(ls, off);
        ps += __shfl_down(ps, off);
    }
    if ((tid & 63) == 0) { la[tid >> 6] = ls; pa[tid >> 6] = ps; }
    __syncthreads();
    if (tid == 0) {
        float L = (la[0] + la[1] + la[2] + la[3]) * (1.25f / (float)((size_t)N_ROWS * D_DIM));
        float P = expf(-(pa[0] + pa[1] + pa[2] + pa[3]));
        *out_loss = L;
        *out_perp = P;
    }
}

extern "C" void kernel_launch(void* const* d_in, const int* in_sizes, int n_in,
                              void* d_out, int out_size, void* d_ws, size_t ws_size,
                              hipStream_t stream) {
    const float* z   = (const float*)d_in[0];
    const float* emb = (const float*)d_in[1];
    float* out = (float*)d_out;

    // output layout (floats): loss | z_q_out | perplexity | min_encodings | idx
    float* out_loss = out;
    float* out_zq   = out + 1;
    float* out_perp = out + 1 + (size_t)N_ROWS * D_DIM;
    float* out_enc  = out_perp + 1;
    float* out_idxf = out_enc + (size_t)N_ROWS * K_CODES;

    char* ws = (char*)d_ws;
    int*   idx_ws    = (int*)ws;                                   // N ints
    int*   counts    = (int*)(ws + (size_t)N_ROWS * 4);            // K ints
    float* loss_part = (float*)(ws + (size_t)N_ROWS * 4 + K_CODES * 4); // 1024 floats
    float* enorm     = loss_part + 1024;                           // 1024 floats

    hipMemsetAsync(counts, 0, K_CODES * sizeof(int), stream);
    hipMemsetAsync(out_enc, 0, (size_t)N_ROWS * K_CODES * sizeof(float), stream);

    k_emb_norm<<<(K_CODES + 255) / 256, 256, 0, stream>>>(emb, enorm);
    k_main<<<N_ROWS / MROWS, 256, 0, stream>>>(z, emb, enorm, idx_ws, counts,
                                               loss_part, out_zq, out_idxf);
    k_ones<<<N_ROWS / 256, 256, 0, stream>>>(idx_ws, out_enc);
    k_final<<<1, 256, 0, stream>>>(loss_part, counts, out_loss, out_perp);
}

// Round 4
// 621.206 us; speedup vs baseline: 1.4440x; 1.4440x over previous
//
#include <hip/hip_runtime.h>
#include <math.h>

#define K_CODES 1024
#define D_DIM   256
#define HW      1024          // 32*32
#define N_ROWS  32768
#define MROWS   32            // rows per block in screen kernel
#define TK      128           // codes per K-tile
#define DC      32            // d-chunk for emb staging
#define TAU     2.0e-4f       // ambiguity margin (quantized-score domain)

// ---------- numpy-faithful pairwise sum of squares (validated round 2) ----------
__device__ __forceinline__ float pw_block128_sq(const float* a) {
    #pragma clang fp contract(off)
    float S[16];
    #pragma unroll
    for (int l = 0; l < 16; ++l) {
        float x0 = a[l],      x4 = a[64 + l];
        float x1 = a[16 + l], x5 = a[80 + l];
        float x2 = a[32 + l], x6 = a[96 + l];
        float x3 = a[48 + l], x7 = a[112 + l];
        float r0 = x0 * x0 + x4 * x4;
        float r1 = x1 * x1 + x5 * x5;
        float r2 = x2 * x2 + x6 * x6;
        float r3 = x3 * x3 + x7 * x7;
        S[l] = (r0 + r1) + (r2 + r3);
    }
    float u0 = S[0] + S[8],  u1 = S[1] + S[9],  u2 = S[2] + S[10], u3 = S[3] + S[11];
    float u4 = S[4] + S[12], u5 = S[5] + S[13], u6 = S[6] + S[14], u7 = S[7] + S[15];
    float v0 = u0 + u4, v1 = u1 + u5, v2 = u2 + u6, v3 = u3 + u7;
    return (v0 + v2) + (v1 + v3);
}
__device__ __forceinline__ float pw_sum256_sq(const float* a) {
    #pragma clang fp contract(off)
    float b0 = pw_block128_sq(a);
    float b1 = pw_block128_sq(a + 128);
    return b0 + b1;
}

// ---------------- K1: emb row norms ----------------
__global__ void k_emb_norm(const float* __restrict__ emb, float* __restrict__ enorm) {
    int k = blockIdx.x * 256 + threadIdx.x;
    if (k < K_CODES) enorm[k] = pw_sum256_sq(emb + (size_t)k * D_DIM);
}

// ---------------- K2: f32 screen ----------------
// Fast f32 scores s = fl(fl(Z+E) - 2*m~). Track best1/best2 per row; rows with
// gap <= TAU go to exact recheck. Certain rows get full epilogue here.
__global__ __launch_bounds__(256, 3) void k_screen(
    const float* __restrict__ z, const float* __restrict__ emb,
    const float* __restrict__ enorm,
    int* __restrict__ idx_ws, int* __restrict__ worklist, int* __restrict__ nflag,
    float* __restrict__ loss_row, float* __restrict__ zq_out,
    float* __restrict__ idxf_out, float* __restrict__ enc)
{
    __shared__ __align__(16) float zl[MROWS][D_DIM + 4];   // 32 x 260 (rows 16B aligned)
    __shared__ __align__(16) float elt[DC][TK + 4];        // 32 x 132, transposed B tile
    __shared__ float zn_sh[MROWS];
    __shared__ int   bestk_sh[MROWS];
    __shared__ unsigned char amb_sh[MROWS];
    __shared__ float lsum_sh[8][MROWS + 1];

    const int blk   = blockIdx.x;
    const int batch = blk >> 5;
    const int p0    = (blk & 31) * MROWS;
    const float* zb = z + (size_t)batch * D_DIM * HW;
    const int tid   = threadIdx.x;

    // stage z tile: zl[p][d] = z[batch][d][p0+p]
    {
        int p = tid & 31;
        for (int d = tid >> 5; d < D_DIM; d += 8)
            zl[p][d] = zb[(size_t)d * HW + p0 + p];
    }
    __syncthreads();
    if (tid < MROWS) zn_sh[tid] = pw_sum256_sq(&zl[tid][0]);
    // zn_sh visibility guaranteed by barriers inside the dc loop

    const int col_grp = tid & 31;   // 32 col groups * 4 cols = 128
    const int row_grp = tid >> 5;   // 8 row groups * 4 rows = 32
    const int r0 = row_grp * 4;

    float b1v[4] = {1e30f, 1e30f, 1e30f, 1e30f};
    float b2v[4] = {1e30f, 1e30f, 1e30f, 1e30f};
    int   b1i[4] = {0, 0, 0, 0};

    for (int kt = 0; kt < K_CODES; kt += TK) {
        float acc[4][4] = {};
        for (int dc = 0; dc < D_DIM; dc += DC) {
            __syncthreads();
            // stage transposed e tile: elt[dd][c] = emb[kt+c][dc+dd]
            {
                int dd4 = (tid & 7) * 4;
                int c0  = tid >> 3;
                #pragma unroll
                for (int rep = 0; rep < 4; ++rep) {
                    int c = c0 + 32 * rep;
                    float4 v = *reinterpret_cast<const float4*>(
                        emb + (size_t)(kt + c) * D_DIM + dc + dd4);
                    elt[dd4 + 0][c] = v.x;
                    elt[dd4 + 1][c] = v.y;
                    elt[dd4 + 2][c] = v.z;
                    elt[dd4 + 3][c] = v.w;
                }
            }
            __syncthreads();
            #pragma unroll
            for (int dd = 0; dd < DC; dd += 4) {
                float4 av[4], bv[4];
                #pragma unroll
                for (int r = 0; r < 4; ++r)
                    av[r] = *reinterpret_cast<const float4*>(&zl[r0 + r][dc + dd]);
                #pragma unroll
                for (int j = 0; j < 4; ++j)
                    bv[j] = *reinterpret_cast<const float4*>(&elt[dd + j][col_grp * 4]);
                #pragma unroll
                for (int r = 0; r < 4; ++r) {
                    float ax = av[r].x, ay = av[r].y, az = av[r].z, aw = av[r].w;
                    acc[r][0] += ax * bv[0].x + ay * bv[1].x + az * bv[2].x + aw * bv[3].x;
                    acc[r][1] += ax * bv[0].y + ay * bv[1].y + az * bv[2].y + aw * bv[3].y;
                    acc[r][2] += ax * bv[0].z + ay * bv[1].z + az * bv[2].z + aw * bv[3].z;
                    acc[r][3] += ax * bv[0].w + ay * bv[1].w + az * bv[2].w + aw * bv[3].w;
                }
            }
        }
        // fold into best1/best2 with quantized score (k ascending per thread)
        #pragma unroll
        for (int c = 0; c < 4; ++c) {
            int k = kt + col_grp * 4 + c;
            float en = enorm[k];
            #pragma unroll
            for (int r = 0; r < 4; ++r) {
                float t1 = zn_sh[r0 + r] + en;
                float s  = t1 - 2.0f * acc[r][c];
                if (s < b1v[r]) { b2v[r] = b1v[r]; b1v[r] = s; b1i[r] = k; }
                else if (s < b2v[r]) b2v[r] = s;
            }
        }
    }

    const int n_base = batch * HW + p0;
    // merge (best1,best2) across the 32 col threads of each half-wave
    #pragma unroll
    for (int r = 0; r < 4; ++r) {
        float v1 = b1v[r]; int i1 = b1i[r]; float v2 = b2v[r];
        #pragma unroll
        for (int o = 16; o >= 1; o >>= 1) {
            float ov1 = __shfl_xor(v1, o);
            int   oi1 = __shfl_xor(i1, o);
            float ov2 = __shfl_xor(v2, o);
            bool take = (ov1 < v1) || (ov1 == v1 && oi1 < i1);
            float loser = take ? v1 : ov1;
            if (take) { v1 = ov1; i1 = oi1; }
            v2 = fminf(fminf(v2, ov2), loser);
        }
        if (col_grp == 0) {
            int row = r0 + r, n = n_base + row;
            bool amb = (v2 - v1) <= TAU;
            bestk_sh[row] = i1;
            amb_sh[row] = amb ? 1 : 0;
            idx_ws[n] = i1;
            if (amb) {
                int slot = atomicAdd(nflag, 1);
                worklist[slot] = n;
            } else {
                idxf_out[n] = (float)i1;
                enc[(size_t)n * K_CODES + i1] = 1.0f;
            }
        }
    }
    __syncthreads();

    // epilogue for certain rows (z still in LDS); loss provisional for flagged
    {
        int p = tid & 31, d0 = tid >> 5;
        int kb = bestk_sh[p];
        bool amb = amb_sh[p] != 0;
        const float* er = emb + (size_t)kb * D_DIM;
        float* zqb = zq_out + (size_t)batch * D_DIM * HW + p0 + p;
        float lsum = 0.0f;
        for (int d = d0; d < D_DIM; d += 8) {
            float e = er[d];
            float diff = e - zl[p][d];
            lsum += diff * diff;
            if (!amb) zqb[(size_t)d * HW] = e;
        }
        lsum_sh[d0][p] = lsum;
    }
    __syncthreads();
    if (tid < MROWS) {
        float L = 0.0f;
        #pragma unroll
        for (int i = 0; i < 8; ++i) L += lsum_sh[i][tid];
        loss_row[n_base + tid] = L;
    }
}

// ---------------- K3: exact f64 recheck for flagged rows (validated math) ----------------
__global__ __launch_bounds__(256) void k_recheck(
    const float* __restrict__ z, const float* __restrict__ emb,
    const float* __restrict__ enorm,
    const int* __restrict__ worklist, const int* __restrict__ nflag,
    int* __restrict__ idx_ws, float* __restrict__ loss_row,
    float* __restrict__ zq_out, float* __restrict__ idxf_out,
    float* __restrict__ enc)
{
    __shared__ __align__(16) float zrow[D_DIM];
    __shared__ float zn_s;
    __shared__ float wv[4]; __shared__ int wi[4];
    __shared__ int kb_s;
    __shared__ float lw[4];

    const int tid = threadIdx.x;
    const int nf = *nflag;
    for (int j = blockIdx.x; j < nf; j += gridDim.x) {
        int n = worklist[j];
        int batch = n >> 10, p = n & (HW - 1);
        zrow[tid] = z[(size_t)batch * D_DIM * HW + (size_t)tid * HW + p];
        __syncthreads();
        if (tid == 0) zn_s = pw_sum256_sq(zrow);
        __syncthreads();

        float bv_ = 1e30f; int bi_ = 0;
        #pragma unroll
        for (int c = 0; c < 4; ++c) {
            int k = tid * 4 + c;
            const float* ek = emb + (size_t)k * D_DIM;
            double acc = 0.0;
            #pragma unroll 4
            for (int d = 0; d < D_DIM; d += 4) {
                float4 e4 = *reinterpret_cast<const float4*>(ek + d);
                float4 z4 = *reinterpret_cast<const float4*>(&zrow[d]);
                acc += (double)z4.x * (double)e4.x + (double)z4.y * (double)e4.y
                     + (double)z4.z * (double)e4.z + (double)z4.w * (double)e4.w;
            }
            {
                #pragma clang fp contract(off)
                float mf = (float)acc;
                float t1 = zn_s + enorm[k];
                float s  = t1 - 2.0f * mf;
                if (s < bv_) { bv_ = s; bi_ = k; }
            }
        }
        #pragma unroll
        for (int o = 32; o >= 1; o >>= 1) {
            float ov = __shfl_xor(bv_, o);
            int   oi = __shfl_xor(bi_, o);
            if (ov < bv_ || (ov == bv_ && oi < bi_)) { bv_ = ov; bi_ = oi; }
        }
        if ((tid & 63) == 0) { wv[tid >> 6] = bv_; wi[tid >> 6] = bi_; }
        __syncthreads();
        if (tid == 0) {
            float fv = wv[0]; int fi = wi[0];
            #pragma unroll
            for (int w = 1; w < 4; ++w)
                if (wv[w] < fv || (wv[w] == fv && wi[w] < fi)) { fv = wv[w]; fi = wi[w]; }
            kb_s = fi;
            idx_ws[n] = fi;
            idxf_out[n] = (float)fi;
            enc[(size_t)n * K_CODES + fi] = 1.0f;
        }
        __syncthreads();
        // epilogue: zq + per-row loss
        {
            int kb = kb_s;
            float e = emb[(size_t)kb * D_DIM + tid];
            float diff = e - zrow[tid];
            float l = diff * diff;
            zq_out[(size_t)batch * D_DIM * HW + (size_t)tid * HW + p] = e;
            #pragma unroll
            for (int o = 32; o >= 1; o >>= 1) l += __shfl_down(l, o);
            if ((tid & 63) == 0) lw[tid >> 6] = l;
        }
        __syncthreads();
        if (tid == 0) loss_row[n] = (lw[0] + lw[1]) + (lw[2] + lw[3]);
        __syncthreads();   // protect zrow/lw before next iteration
    }
}

// ---------------- K4: codebook counts ----------------
__global__ void k_counts(const int* __restrict__ idx_ws, int* __restrict__ counts) {
    int n = blockIdx.x * 256 + threadIdx.x;
    atomicAdd(&counts[idx_ws[n]], 1);
}

// ---------------- K5: finalize loss + perplexity ----------------
__global__ void k_final(const float* __restrict__ loss_row,
                        const int* __restrict__ counts,
                        float* __restrict__ out_loss, float* __restrict__ out_perp) {
    __shared__ float la[4], pa[4];
    int tid = threadIdx.x;
    float ls = 0.0f, ps = 0.0f;
    for (int i = tid; i < N_ROWS; i += 256) ls += loss_row[i];
    for (int i = tid; i < K_CODES; i += 256) {
        float em = (float)counts[i] * (1.0f / (float)N_ROWS);
        ps += em * logf(em + 1e-10f);
    }
    #pragma unroll
    for (int off = 32; off > 0; off >>= 1) {
        ls += __shfl_down(ls, off);
        ps += __shfl_down(ps, off);
    }
    if ((tid & 63) == 0) { la[tid >> 6] = ls; pa[tid >> 6] = ps; }
    __syncthreads();
    if (tid == 0) {
        float L = (la[0] + la[1] + la[2] + la[3]) * (1.25f / (float)((size_t)N_ROWS * D_DIM));
        float P = expf(-(pa[0] + pa[1] + pa[2] + pa[3]));
        *out_loss = L;
        *out_perp = P;
    }
}

extern "C" void kernel_launch(void* const* d_in, const int* in_sizes, int n_in,
                              void* d_out, int out_size, void* d_ws, size_t ws_size,
                              hipStream_t stream) {
    const float* z   = (const float*)d_in[0];
    const float* emb = (const float*)d_in[1];
    float* out = (float*)d_out;

    // output layout (floats): loss | z_q_out | perplexity | min_encodings | idx
    float* out_loss = out;
    float* out_zq   = out + 1;
    float* out_perp = out + 1 + (size_t)N_ROWS * D_DIM;
    float* out_enc  = out_perp + 1;
    float* out_idxf = out_enc + (size_t)N_ROWS * K_CODES;

    char* ws = (char*)d_ws;
    int*   idx_ws    = (int*)ws;                                   // 128 KB
    int*   counts    = (int*)(ws + 131072);                        // 4 KB
    float* enorm     = (float*)(ws + 131072 + 4096);               // 4 KB
    float* loss_row  = (float*)(ws + 131072 + 8192);               // 128 KB
    int*   worklist  = (int*)(ws + 262144 + 8192);                 // 128 KB
    int*   nflag     = (int*)(ws + 393216 + 8192);                 // 4 B

    hipMemsetAsync(counts, 0, K_CODES * sizeof(int), stream);
    hipMemsetAsync(nflag, 0, sizeof(int), stream);
    hipMemsetAsync(out_enc, 0, (size_t)N_ROWS * K_CODES * sizeof(float), stream);

    k_emb_norm<<<(K_CODES + 255) / 256, 256, 0, stream>>>(emb, enorm);
    k_screen<<<N_ROWS / MROWS, 256, 0, stream>>>(z, emb, enorm, idx_ws, worklist,
                                                 nflag, loss_row, out_zq,
                                                 out_idxf, out_enc);
    k_recheck<<<1024, 256, 0, stream>>>(z, emb, enorm, worklist, nflag, idx_ws,
                                        loss_row, out_zq, out_idxf, out_enc);
    k_counts<<<N_ROWS / 256, 256, 0, stream>>>(idx_ws, counts);
    k_final<<<1, 256, 0, stream>>>(loss_row, counts, out_loss, out_perp);
}

// Round 5
// 412.239 us; speedup vs baseline: 2.1760x; 1.5069x over previous
//
#include <hip/hip_runtime.h>
#include <math.h>

#define K_CODES 1024
#define D_DIM   256
#define HW      1024          // 32*32
#define N_ROWS  32768
#define TAU     2.0e-4f       // ambiguity margin (quantized-score domain)

typedef __attribute__((ext_vector_type(8))) short bf16x8;
typedef __attribute__((ext_vector_type(4))) float f32x4;
#define MFMA16(a, b, c) __builtin_amdgcn_mfma_f32_16x16x32_bf16(a, b, c, 0, 0, 0)

__device__ __forceinline__ unsigned bf16_rne_bits(float x) {
    unsigned u = __float_as_uint(x);
    return (u + 0x7FFFu + ((u >> 16) & 1u)) >> 16;
}

// ---------- numpy-faithful pairwise sum of squares (validated round 2) ----------
__device__ __forceinline__ float pw_block128_sq(const float* a) {
    #pragma clang fp contract(off)
    float S[16];
    #pragma unroll
    for (int l = 0; l < 16; ++l) {
        float x0 = a[l],      x4 = a[64 + l];
        float x1 = a[16 + l], x5 = a[80 + l];
        float x2 = a[32 + l], x6 = a[96 + l];
        float x3 = a[48 + l], x7 = a[112 + l];
        float r0 = x0 * x0 + x4 * x4;
        float r1 = x1 * x1 + x5 * x5;
        float r2 = x2 * x2 + x6 * x6;
        float r3 = x3 * x3 + x7 * x7;
        S[l] = (r0 + r1) + (r2 + r3);
    }
    float u0 = S[0] + S[8],  u1 = S[1] + S[9],  u2 = S[2] + S[10], u3 = S[3] + S[11];
    float u4 = S[4] + S[12], u5 = S[5] + S[13], u6 = S[6] + S[14], u7 = S[7] + S[15];
    float v0 = u0 + u4, v1 = u1 + u5, v2 = u2 + u6, v3 = u3 + u7;
    return (v0 + v2) + (v1 + v3);
}
__device__ __forceinline__ float pw_sum256_sq(const float* a) {
    #pragma clang fp contract(off)
    float b0 = pw_block128_sq(a);
    float b1 = pw_block128_sq(a + 128);
    return b0 + b1;
}

// ---------------- K0: emb -> bf16 hi/lo split ----------------
__global__ void k_emb_cvt(const float* __restrict__ emb,
                          ushort* __restrict__ hi, ushort* __restrict__ lo) {
    int i = blockIdx.x * 256 + threadIdx.x;   // 65536 float4 groups
    float4 v = reinterpret_cast<const float4*>(emb)[i];
    ushort4 h, l;
    float x[4] = {v.x, v.y, v.z, v.w};
    ushort hb[4], lb[4];
    #pragma unroll
    for (int j = 0; j < 4; ++j) {
        unsigned hbits = bf16_rne_bits(x[j]);
        float hf = __uint_as_float(hbits << 16);
        unsigned lbits = bf16_rne_bits(x[j] - hf);
        hb[j] = (ushort)hbits; lb[j] = (ushort)lbits;
    }
    h.x = hb[0]; h.y = hb[1]; h.z = hb[2]; h.w = hb[3];
    l.x = lb[0]; l.y = lb[1]; l.z = lb[2]; l.w = lb[3];
    reinterpret_cast<ushort4*>(hi)[i] = h;
    reinterpret_cast<ushort4*>(lo)[i] = l;
}

// ---------------- K1: emb row norms (numpy-faithful) ----------------
__global__ void k_emb_norm(const float* __restrict__ emb, float* __restrict__ enorm) {
    int k = blockIdx.x * 256 + threadIdx.x;
    if (k < K_CODES) enorm[k] = pw_sum256_sq(emb + (size_t)k * D_DIM);
}

// ---------------- K2: MFMA screen ----------------
// Block: 256 thr (4 waves). 64 rows/block, wave owns 16 rows (A in VGPRs).
// K-loop over 64 tiles of 16 codes; B (hi/lo bf16) double-buffered in LDS.
// Scores s = fl(fl(zn+en) - 2*m); track best1/best2; flag gap<=TAU rows.
#define BT_STR 264              // padded ushort stride (16B-aligned rows)
#define BT_BLK (16 * BT_STR)    // one 16-code half-tile (hi or lo)
__global__ __launch_bounds__(256, 2) void k_screen_mfma(
    const float* __restrict__ z,
    const ushort* __restrict__ emb_hi, const ushort* __restrict__ emb_lo,
    const float* __restrict__ enorm,
    int* __restrict__ idx_ws, int* __restrict__ worklist, int* __restrict__ nflag)
{
    __shared__ __align__(16) float zl[64 * 257];   // 65792 B; reused as B tiles
    __shared__ float enorm_lds[K_CODES];
    __shared__ float zn_sh[64];

    const int tid  = threadIdx.x;
    const int lane = tid & 63, wave = tid >> 6;
    const int blk  = blockIdx.x;                   // 512 blocks
    const int batch = blk >> 4;
    const int p0    = (blk & 15) * 64;
    const float* zb = z + (size_t)batch * D_DIM * HW;

    // stage z tile (f32): zl[p*257 + d] = z[batch][d][p0+p]
    {
        int p = tid & 63;
        for (int d = tid >> 6; d < D_DIM; d += 4)
            zl[p * 257 + d] = zb[(size_t)d * HW + p0 + p];
    }
    // stage enorm
    for (int i = tid; i < K_CODES; i += 256) enorm_lds[i] = enorm[i];
    __syncthreads();

    // numpy-faithful zn per row
    if (tid < 64) zn_sh[tid] = pw_sum256_sq(&zl[tid * 257]);

    // build A fragments in registers (hi/lo bf16), 16 rows per wave
    const int fr = lane & 15, fg = lane >> 4;
    bf16x8 Ah[8], Al[8];
    {
        const float* zr = &zl[(wave * 16 + fr) * 257];
        #pragma unroll
        for (int s = 0; s < 8; ++s) {
            int c0 = s * 32 + fg * 8;
            bf16x8 h, l;
            #pragma unroll
            for (int j = 0; j < 8; ++j) {
                float x = zr[c0 + j];
                unsigned hb = bf16_rne_bits(x);
                float hf = __uint_as_float(hb << 16);
                unsigned lb = bf16_rne_bits(x - hf);
                h[j] = (short)hb; l[j] = (short)lb;
            }
            Ah[s] = h; Al[s] = l;
        }
    }
    __syncthreads();   // zl (f32) dead; B tiles may now overwrite it

    ushort* bt = reinterpret_cast<ushort*>(zl);    // [2 buf][hi,lo][16][BT_STR]

    // stage helper: tile kt -> buffer buf
    auto stage = [&](int buf, int kt) {
        int row = tid >> 5, d16 = tid & 31;
        #pragma unroll
        for (int i = 0; i < 2; ++i) {
            int r = row + 8 * i;
            size_t src = ((size_t)(kt * 16 + r) << 8) + d16 * 8;
            uint4 vh = *reinterpret_cast<const uint4*>(emb_hi + src);
            uint4 vl = *reinterpret_cast<const uint4*>(emb_lo + src);
            *reinterpret_cast<uint4*>(&bt[(buf * 2 + 0) * BT_BLK + r * BT_STR + d16 * 8]) = vh;
            *reinterpret_cast<uint4*>(&bt[(buf * 2 + 1) * BT_BLK + r * BT_STR + d16 * 8]) = vl;
        }
    };

    float zn4[4];
    #pragma unroll
    for (int r = 0; r < 4; ++r) zn4[r] = zn_sh[wave * 16 + fg * 4 + r];

    float b1v[4] = {1e30f, 1e30f, 1e30f, 1e30f};
    float b2v[4] = {1e30f, 1e30f, 1e30f, 1e30f};
    int   b1i[4] = {0, 0, 0, 0};

    stage(0, 0);
    __syncthreads();

    const int boff = fr * BT_STR + fg * 8;
    for (int kt = 0; kt < 64; ++kt) {
        int cur = kt & 1;
        if (kt < 63) stage(cur ^ 1, kt + 1);

        f32x4 aHH = {0.f, 0.f, 0.f, 0.f};
        f32x4 aHM = {0.f, 0.f, 0.f, 0.f};
        f32x4 aLH = {0.f, 0.f, 0.f, 0.f};
        const ushort* bhp = bt + cur * 2 * BT_BLK + boff;
        const ushort* blp = bhp + BT_BLK;
        #pragma unroll
        for (int s = 0; s < 8; ++s) {
            bf16x8 Bh = *reinterpret_cast<const bf16x8*>(bhp + s * 32);
            bf16x8 Bl = *reinterpret_cast<const bf16x8*>(blp + s * 32);
            aHH = MFMA16(Ah[s], Bh, aHH);
            aHM = MFMA16(Ah[s], Bl, aHM);
            aLH = MFMA16(Al[s], Bh, aLH);
        }
        {
            #pragma clang fp contract(off)
            float en = enorm_lds[kt * 16 + fr];
            int kk = kt * 16 + fr;
            #pragma unroll
            for (int r = 0; r < 4; ++r) {
                float m  = aHH[r] + (aHM[r] + aLH[r]);
                float t1 = zn4[r] + en;
                float s  = t1 - 2.0f * m;
                if (s < b1v[r]) { b2v[r] = b1v[r]; b1v[r] = s; b1i[r] = kk; }
                else if (s < b2v[r]) b2v[r] = s;
            }
        }
        __syncthreads();
    }

    // merge best1/best2 across the 16 lanes of each row group
    const int n0w = blk * 64 + wave * 16;
    #pragma unroll
    for (int r = 0; r < 4; ++r) {
        float v1 = b1v[r]; int i1 = b1i[r]; float v2 = b2v[r];
        #pragma unroll
        for (int o = 8; o >= 1; o >>= 1) {
            float ov1 = __shfl_xor(v1, o);
            int   oi1 = __shfl_xor(i1, o);
            float ov2 = __shfl_xor(v2, o);
            bool take = (ov1 < v1) || (ov1 == v1 && oi1 < i1);
            float loser = take ? v1 : ov1;
            if (take) { v1 = ov1; i1 = oi1; }
            v2 = fminf(fminf(v2, ov2), loser);
        }
        if (fr == 0) {
            int n = n0w + fg * 4 + r;
            idx_ws[n] = i1;
            if (v2 - v1 <= TAU) {
                int slot = atomicAdd(nflag, 1);
                worklist[slot] = n;
            }
        }
    }
}

// ---------------- K3: epilogue (zq, loss, idxf, enc ones) ----------------
__global__ __launch_bounds__(256) void k_epilogue(
    const float* __restrict__ z, const float* __restrict__ emb,
    const int* __restrict__ idx_ws,
    float* __restrict__ zq_out, float* __restrict__ idxf_out,
    float* __restrict__ enc, float* __restrict__ loss_row)
{
    __shared__ int kb[64];
    __shared__ float lpart[4][64];
    const int tid = threadIdx.x;
    const int blk = blockIdx.x;                 // 512
    const int batch = blk >> 4;
    const int p0 = (blk & 15) * 64;
    const int n0 = blk * 64;

    if (tid < 64) {
        int k = idx_ws[n0 + tid];
        kb[tid] = k;
        idxf_out[n0 + tid] = (float)k;
        enc[(size_t)(n0 + tid) * K_CODES + k] = 1.0f;
    }
    __syncthreads();

    int p = tid & 63, dg = tid >> 6;
    const float* zp = z + (size_t)batch * D_DIM * HW + p0 + p;
    float* zqp = zq_out + (size_t)batch * D_DIM * HW + p0 + p;
    const float* er = emb + (size_t)kb[p] * D_DIM;
    float ls = 0.0f;
    for (int d = dg * 64; d < dg * 64 + 64; ++d) {
        float e = er[d];
        float zv = zp[(size_t)d * HW];
        float df = e - zv;
        ls += df * df;
        zqp[(size_t)d * HW] = e;
    }
    lpart[dg][p] = ls;
    __syncthreads();
    if (tid < 64)
        loss_row[n0 + tid] = (lpart[0][tid] + lpart[1][tid]) + (lpart[2][tid] + lpart[3][tid]);
}

// ---------------- K4: exact f64 recheck for flagged rows (validated) ----------------
__global__ __launch_bounds__(256) void k_recheck(
    const float* __restrict__ z, const float* __restrict__ emb,
    const float* __restrict__ enorm,
    const int* __restrict__ worklist, const int* __restrict__ nflag,
    int* __restrict__ idx_ws, float* __restrict__ loss_row,
    float* __restrict__ zq_out, float* __restrict__ idxf_out,
    float* __restrict__ enc)
{
    __shared__ __align__(16) float zrow[D_DIM];
    __shared__ float zn_s;
    __shared__ float wv[4]; __shared__ int wi[4];
    __shared__ int kb_s;
    __shared__ float lw[4];

    const int tid = threadIdx.x;
    const int nf = *nflag;
    for (int j = blockIdx.x; j < nf; j += gridDim.x) {
        int n = worklist[j];
        int batch = n >> 10, p = n & (HW - 1);
        zrow[tid] = z[(size_t)batch * D_DIM * HW + (size_t)tid * HW + p];
        __syncthreads();
        if (tid == 0) zn_s = pw_sum256_sq(zrow);
        __syncthreads();

        float bv_ = 1e30f; int bi_ = 0;
        #pragma unroll
        for (int c = 0; c < 4; ++c) {
            int k = tid * 4 + c;
            const float* ek = emb + (size_t)k * D_DIM;
            double acc = 0.0;
            #pragma unroll 4
            for (int d = 0; d < D_DIM; d += 4) {
                float4 e4 = *reinterpret_cast<const float4*>(ek + d);
                float4 z4 = *reinterpret_cast<const float4*>(&zrow[d]);
                acc += (double)z4.x * (double)e4.x + (double)z4.y * (double)e4.y
                     + (double)z4.z * (double)e4.z + (double)z4.w * (double)e4.w;
            }
            {
                #pragma clang fp contract(off)
                float mf = (float)acc;
                float t1 = zn_s + enorm[k];
                float s  = t1 - 2.0f * mf;
                if (s < bv_) { bv_ = s; bi_ = k; }
            }
        }
        #pragma unroll
        for (int o = 32; o >= 1; o >>= 1) {
            float ov = __shfl_xor(bv_, o);
            int   oi = __shfl_xor(bi_, o);
            if (ov < bv_ || (ov == bv_ && oi < bi_)) { bv_ = ov; bi_ = oi; }
        }
        if ((tid & 63) == 0) { wv[tid >> 6] = bv_; wi[tid >> 6] = bi_; }
        __syncthreads();
        if (tid == 0) {
            float fv = wv[0]; int fi = wi[0];
            #pragma unroll
            for (int w = 1; w < 4; ++w)
                if (wv[w] < fv || (wv[w] == fv && wi[w] < fi)) { fv = wv[w]; fi = wi[w]; }
            int old = idx_ws[n];
            kb_s = fi;
            idx_ws[n] = fi;
            idxf_out[n] = (float)fi;
            if (old != fi) enc[(size_t)n * K_CODES + old] = 0.0f;
            enc[(size_t)n * K_CODES + fi] = 1.0f;
        }
        __syncthreads();
        // epilogue: zq + per-row loss
        {
            int kbv = kb_s;
            float e = emb[(size_t)kbv * D_DIM + tid];
            float diff = e - zrow[tid];
            float l = diff * diff;
            zq_out[(size_t)batch * D_DIM * HW + (size_t)tid * HW + p] = e;
            #pragma unroll
            for (int o = 32; o >= 1; o >>= 1) l += __shfl_down(l, o);
            if ((tid & 63) == 0) lw[tid >> 6] = l;
        }
        __syncthreads();
        if (tid == 0) loss_row[n] = (lw[0] + lw[1]) + (lw[2] + lw[3]);
        __syncthreads();
    }
}

// ---------------- K5: codebook counts ----------------
__global__ void k_counts(const int* __restrict__ idx_ws, int* __restrict__ counts) {
    int n = blockIdx.x * 256 + threadIdx.x;
    atomicAdd(&counts[idx_ws[n]], 1);
}

// ---------------- K6: finalize loss + perplexity ----------------
__global__ void k_final(const float* __restrict__ loss_row,
                        const int* __restrict__ counts,
                        float* __restrict__ out_loss, float* __restrict__ out_perp) {
    __shared__ float la[4], pa[4];
    int tid = threadIdx.x;
    float ls = 0.0f, ps = 0.0f;
    for (int i = tid; i < N_ROWS; i += 256) ls += loss_row[i];
    for (int i = tid; i < K_CODES; i += 256) {
        float em = (float)counts[i] * (1.0f / (float)N_ROWS);
        ps += em * logf(em + 1e-10f);
    }
    #pragma unroll
    for (int off = 32; off > 0; off >>= 1) {
        ls += __shfl_down(ls, off);
        ps += __shfl_down(ps, off);
    }
    if ((tid & 63) == 0) { la[tid >> 6] = ls; pa[tid >> 6] = ps; }
    __syncthreads();
    if (tid == 0) {
        float L = (la[0] + la[1] + la[2] + la[3]) * (1.25f / (float)((size_t)N_ROWS * D_DIM));
        float P = expf(-(pa[0] + pa[1] + pa[2] + pa[3]));
        *out_loss = L;
        *out_perp = P;
    }
}

extern "C" void kernel_launch(void* const* d_in, const int* in_sizes, int n_in,
                              void* d_out, int out_size, void* d_ws, size_t ws_size,
                              hipStream_t stream) {
    const float* z   = (const float*)d_in[0];
    const float* emb = (const float*)d_in[1];
    float* out = (float*)d_out;

    // output layout (floats): loss | z_q_out | perplexity | min_encodings | idx
    float* out_loss = out;
    float* out_zq   = out + 1;
    float* out_perp = out + 1 + (size_t)N_ROWS * D_DIM;
    float* out_enc  = out_perp + 1;
    float* out_idxf = out_enc + (size_t)N_ROWS * K_CODES;

    char* ws = (char*)d_ws;
    int*    idx_ws   = (int*)(ws + 0);          // 131072 B
    int*    counts   = (int*)(ws + 131072);     // 4096 B
    float*  enorm    = (float*)(ws + 135168);   // 4096 B
    float*  loss_row = (float*)(ws + 139264);   // 131072 B
    int*    worklist = (int*)(ws + 270336);     // 131072 B
    int*    nflag    = (int*)(ws + 401408);     // 256 B
    ushort* emb_hi   = (ushort*)(ws + 401664);  // 524288 B
    ushort* emb_lo   = (ushort*)(ws + 925952);  // 524288 B

    hipMemsetAsync(counts, 0, K_CODES * sizeof(int), stream);
    hipMemsetAsync(nflag, 0, sizeof(int), stream);
    hipMemsetAsync(out_enc, 0, (size_t)N_ROWS * K_CODES * sizeof(float), stream);

    k_emb_cvt<<<256, 256, 0, stream>>>(emb, emb_hi, emb_lo);
    k_emb_norm<<<(K_CODES + 255) / 256, 256, 0, stream>>>(emb, enorm);
    k_screen_mfma<<<512, 256, 0, stream>>>(z, emb_hi, emb_lo, enorm,
                                           idx_ws, worklist, nflag);
    k_epilogue<<<512, 256, 0, stream>>>(z, emb, idx_ws, out_zq, out_idxf,
                                        out_enc, loss_row);
    k_recheck<<<1024, 256, 0, stream>>>(z, emb, enorm, worklist, nflag, idx_ws,
                                        loss_row, out_zq, out_idxf, out_enc);
    k_counts<<<N_ROWS / 256, 256, 0, stream>>>(idx_ws, counts);
    k_final<<<1, 256, 0, stream>>>(loss_row, counts, out_loss, out_perp);
}

// Round 6
// 410.905 us; speedup vs baseline: 2.1830x; 1.0032x over previous
//
#include <hip/hip_runtime.h>
#include <math.h>

#define K_CODES 1024
#define D_DIM   256
#define HW      1024          // 32*32
#define N_ROWS  32768
#define TAU     2.0e-4f       // ambiguity margin (quantized-score domain)

typedef __attribute__((ext_vector_type(8))) short bf16x8;
typedef __attribute__((ext_vector_type(4))) float f32x4;
#define MFMA16(a, b, c) __builtin_amdgcn_mfma_f32_16x16x32_bf16(a, b, c, 0, 0, 0)

__device__ __forceinline__ unsigned bf16_rne_bits(float x) {
    unsigned u = __float_as_uint(x);
    return (u + 0x7FFFu + ((u >> 16) & 1u)) >> 16;
}

// ---------- numpy-faithful pairwise sum of squares (validated round 2) ----------
__device__ __forceinline__ float pw_block128_sq(const float* a) {
    #pragma clang fp contract(off)
    float S[16];
    #pragma unroll
    for (int l = 0; l < 16; ++l) {
        float x0 = a[l],      x4 = a[64 + l];
        float x1 = a[16 + l], x5 = a[80 + l];
        float x2 = a[32 + l], x6 = a[96 + l];
        float x3 = a[48 + l], x7 = a[112 + l];
        float r0 = x0 * x0 + x4 * x4;
        float r1 = x1 * x1 + x5 * x5;
        float r2 = x2 * x2 + x6 * x6;
        float r3 = x3 * x3 + x7 * x7;
        S[l] = (r0 + r1) + (r2 + r3);
    }
    float u0 = S[0] + S[8],  u1 = S[1] + S[9],  u2 = S[2] + S[10], u3 = S[3] + S[11];
    float u4 = S[4] + S[12], u5 = S[5] + S[13], u6 = S[6] + S[14], u7 = S[7] + S[15];
    float v0 = u0 + u4, v1 = u1 + u5, v2 = u2 + u6, v3 = u3 + u7;
    return (v0 + v2) + (v1 + v3);
}
__device__ __forceinline__ float pw_sum256_sq(const float* a) {
    #pragma clang fp contract(off)
    float b0 = pw_block128_sq(a);
    float b1 = pw_block128_sq(a + 128);
    return b0 + b1;
}

// ---------------- K0: emb -> bf16 hi/lo split ----------------
__global__ void k_emb_cvt(const float* __restrict__ emb,
                          ushort* __restrict__ hi, ushort* __restrict__ lo) {
    int i = blockIdx.x * 256 + threadIdx.x;   // 65536 float4 groups
    float4 v = reinterpret_cast<const float4*>(emb)[i];
    ushort4 h, l;
    float x[4] = {v.x, v.y, v.z, v.w};
    ushort hb[4], lb[4];
    #pragma unroll
    for (int j = 0; j < 4; ++j) {
        unsigned hbits = bf16_rne_bits(x[j]);
        float hf = __uint_as_float(hbits << 16);
        unsigned lbits = bf16_rne_bits(x[j] - hf);
        hb[j] = (ushort)hbits; lb[j] = (ushort)lbits;
    }
    h.x = hb[0]; h.y = hb[1]; h.z = hb[2]; h.w = hb[3];
    l.x = lb[0]; l.y = lb[1]; l.z = lb[2]; l.w = lb[3];
    reinterpret_cast<ushort4*>(hi)[i] = h;
    reinterpret_cast<ushort4*>(lo)[i] = l;
}

// ---------------- K1: emb row norms (numpy-faithful) ----------------
__global__ void k_emb_norm(const float* __restrict__ emb, float* __restrict__ enorm) {
    int k = blockIdx.x * 256 + threadIdx.x;
    if (k < K_CODES) enorm[k] = pw_sum256_sq(emb + (size_t)k * D_DIM);
}

// ---------------- K2: MFMA screen ----------------
// Block: 256 thr (4 waves). 64 rows/block, wave owns 16 rows (A in VGPRs).
// K-loop over 64 tiles of 16 codes; B (hi/lo bf16) double-buffered in LDS.
// Scores s = fl(fl(zn+en) - 2*m); track best1/best2; flag gap<=TAU rows.
#define BT_STR 264              // padded ushort stride (16B-aligned rows)
#define BT_BLK (16 * BT_STR)    // one 16-code half-tile (hi or lo)
__global__ __launch_bounds__(256, 2) void k_screen_mfma(
    const float* __restrict__ z,
    const ushort* __restrict__ emb_hi, const ushort* __restrict__ emb_lo,
    const float* __restrict__ enorm,
    int* __restrict__ idx_ws, int* __restrict__ worklist, int* __restrict__ nflag)
{
    __shared__ __align__(16) float zl[64 * 257];   // 65792 B; reused as B tiles
    __shared__ float enorm_lds[K_CODES];
    __shared__ float zn_sh[64];

    const int tid  = threadIdx.x;
    const int lane = tid & 63, wave = tid >> 6;
    const int blk  = blockIdx.x;                   // 512 blocks
    const int batch = blk >> 4;
    const int p0    = (blk & 15) * 64;
    const float* zb = z + (size_t)batch * D_DIM * HW;

    // stage z tile (f32): zl[p*257 + d] = z[batch][d][p0+p]
    {
        int p = tid & 63;
        for (int d = tid >> 6; d < D_DIM; d += 4)
            zl[p * 257 + d] = zb[(size_t)d * HW + p0 + p];
    }
    // stage enorm
    for (int i = tid; i < K_CODES; i += 256) enorm_lds[i] = enorm[i];
    __syncthreads();

    // numpy-faithful zn per row
    if (tid < 64) zn_sh[tid] = pw_sum256_sq(&zl[tid * 257]);

    // build A fragments in registers (hi/lo bf16), 16 rows per wave
    const int fr = lane & 15, fg = lane >> 4;
    bf16x8 Ah[8], Al[8];
    {
        const float* zr = &zl[(wave * 16 + fr) * 257];
        #pragma unroll
        for (int s = 0; s < 8; ++s) {
            int c0 = s * 32 + fg * 8;
            bf16x8 h, l;
            #pragma unroll
            for (int j = 0; j < 8; ++j) {
                float x = zr[c0 + j];
                unsigned hb = bf16_rne_bits(x);
                float hf = __uint_as_float(hb << 16);
                unsigned lb = bf16_rne_bits(x - hf);
                h[j] = (short)hb; l[j] = (short)lb;
            }
            Ah[s] = h; Al[s] = l;
        }
    }
    __syncthreads();   // zl (f32) dead; B tiles may now overwrite it

    ushort* bt = reinterpret_cast<ushort*>(zl);    // [2 buf][hi,lo][16][BT_STR]

    // stage helper: tile kt -> buffer buf
    auto stage = [&](int buf, int kt) {
        int row = tid >> 5, d16 = tid & 31;
        #pragma unroll
        for (int i = 0; i < 2; ++i) {
            int r = row + 8 * i;
            size_t src = ((size_t)(kt * 16 + r) << 8) + d16 * 8;
            uint4 vh = *reinterpret_cast<const uint4*>(emb_hi + src);
            uint4 vl = *reinterpret_cast<const uint4*>(emb_lo + src);
            *reinterpret_cast<uint4*>(&bt[(buf * 2 + 0) * BT_BLK + r * BT_STR + d16 * 8]) = vh;
            *reinterpret_cast<uint4*>(&bt[(buf * 2 + 1) * BT_BLK + r * BT_STR + d16 * 8]) = vl;
        }
    };

    float zn4[4];
    #pragma unroll
    for (int r = 0; r < 4; ++r) zn4[r] = zn_sh[wave * 16 + fg * 4 + r];

    float b1v[4] = {1e30f, 1e30f, 1e30f, 1e30f};
    float b2v[4] = {1e30f, 1e30f, 1e30f, 1e30f};
    int   b1i[4] = {0, 0, 0, 0};

    stage(0, 0);
    __syncthreads();

    const int boff = fr * BT_STR + fg * 8;
    for (int kt = 0; kt < 64; ++kt) {
        int cur = kt & 1;
        if (kt < 63) stage(cur ^ 1, kt + 1);

        f32x4 aHH = {0.f, 0.f, 0.f, 0.f};
        f32x4 aHM = {0.f, 0.f, 0.f, 0.f};
        f32x4 aLH = {0.f, 0.f, 0.f, 0.f};
        const ushort* bhp = bt + cur * 2 * BT_BLK + boff;
        const ushort* blp = bhp + BT_BLK;
        #pragma unroll
        for (int s = 0; s < 8; ++s) {
            bf16x8 Bh = *reinterpret_cast<const bf16x8*>(bhp + s * 32);
            bf16x8 Bl = *reinterpret_cast<const bf16x8*>(blp + s * 32);
            aHH = MFMA16(Ah[s], Bh, aHH);
            aHM = MFMA16(Ah[s], Bl, aHM);
            aLH = MFMA16(Al[s], Bh, aLH);
        }
        {
            #pragma clang fp contract(off)
            float en = enorm_lds[kt * 16 + fr];
            int kk = kt * 16 + fr;
            #pragma unroll
            for (int r = 0; r < 4; ++r) {
                float m  = aHH[r] + (aHM[r] + aLH[r]);
                float t1 = zn4[r] + en;
                float s  = t1 - 2.0f * m;
                if (s < b1v[r]) { b2v[r] = b1v[r]; b1v[r] = s; b1i[r] = kk; }
                else if (s < b2v[r]) b2v[r] = s;
            }
        }
        __syncthreads();
    }

    // merge best1/best2 across the 16 lanes of each row group
    const int n0w = blk * 64 + wave * 16;
    #pragma unroll
    for (int r = 0; r < 4; ++r) {
        float v1 = b1v[r]; int i1 = b1i[r]; float v2 = b2v[r];
        #pragma unroll
        for (int o = 8; o >= 1; o >>= 1) {
            float ov1 = __shfl_xor(v1, o);
            int   oi1 = __shfl_xor(i1, o);
            float ov2 = __shfl_xor(v2, o);
            bool take = (ov1 < v1) || (ov1 == v1 && oi1 < i1);
            float loser = take ? v1 : ov1;
            if (take) { v1 = ov1; i1 = oi1; }
            v2 = fminf(fminf(v2, ov2), loser);
        }
        if (fr == 0) {
            int n = n0w + fg * 4 + r;
            idx_ws[n] = i1;
            if (v2 - v1 <= TAU) {
                int slot = atomicAdd(nflag, 1);
                worklist[slot] = n;
            }
        }
    }
}

// ---------------- K3: epilogue (zq, loss, idxf, enc ones) ----------------
__global__ __launch_bounds__(256) void k_epilogue(
    const float* __restrict__ z, const float* __restrict__ emb,
    const int* __restrict__ idx_ws,
    float* __restrict__ zq_out, float* __restrict__ idxf_out,
    float* __restrict__ enc, float* __restrict__ loss_row)
{
    __shared__ int kb[64];
    __shared__ float lpart[4][64];
    const int tid = threadIdx.x;
    const int blk = blockIdx.x;                 // 512
    const int batch = blk >> 4;
    const int p0 = (blk & 15) * 64;
    const int n0 = blk * 64;

    if (tid < 64) {
        int k = idx_ws[n0 + tid];
        kb[tid] = k;
        idxf_out[n0 + tid] = (float)k;
        enc[(size_t)(n0 + tid) * K_CODES + k] = 1.0f;
    }
    __syncthreads();

    int p = tid & 63, dg = tid >> 6;
    const float* zp = z + (size_t)batch * D_DIM * HW + p0 + p;
    float* zqp = zq_out + (size_t)batch * D_DIM * HW + p0 + p;
    const float* er = emb + (size_t)kb[p] * D_DIM;
    float ls = 0.0f;
    for (int d = dg * 64; d < dg * 64 + 64; ++d) {
        float e = er[d];
        float zv = zp[(size_t)d * HW];
        float df = e - zv;
        ls += df * df;
        zqp[(size_t)d * HW] = e;
    }
    lpart[dg][p] = ls;
    __syncthreads();
    if (tid < 64)
        loss_row[n0 + tid] = (lpart[0][tid] + lpart[1][tid]) + (lpart[2][tid] + lpart[3][tid]);
}

// ---------------- K4: exact f64 recheck for flagged rows (validated) ----------------
__global__ __launch_bounds__(256) void k_recheck(
    const float* __restrict__ z, const float* __restrict__ emb,
    const float* __restrict__ enorm,
    const int* __restrict__ worklist, const int* __restrict__ nflag,
    int* __restrict__ idx_ws, float* __restrict__ loss_row,
    float* __restrict__ zq_out, float* __restrict__ idxf_out,
    float* __restrict__ enc)
{
    __shared__ __align__(16) float zrow[D_DIM];
    __shared__ float zn_s;
    __shared__ float wv[4]; __shared__ int wi[4];
    __shared__ int kb_s;
    __shared__ float lw[4];

    const int tid = threadIdx.x;
    const int nf = *nflag;
    for (int j = blockIdx.x; j < nf; j += gridDim.x) {
        int n = worklist[j];
        int batch = n >> 10, p = n & (HW - 1);
        zrow[tid] = z[(size_t)batch * D_DIM * HW + (size_t)tid * HW + p];
        __syncthreads();
        if (tid == 0) zn_s = pw_sum256_sq(zrow);
        __syncthreads();

        float bv_ = 1e30f; int bi_ = 0;
        #pragma unroll
        for (int c = 0; c < 4; ++c) {
            int k = tid * 4 + c;
            const float* ek = emb + (size_t)k * D_DIM;
            double acc = 0.0;
            #pragma unroll 4
            for (int d = 0; d < D_DIM; d += 4) {
                float4 e4 = *reinterpret_cast<const float4*>(ek + d);
                float4 z4 = *reinterpret_cast<const float4*>(&zrow[d]);
                acc += (double)z4.x * (double)e4.x + (double)z4.y * (double)e4.y
                     + (double)z4.z * (double)e4.z + (double)z4.w * (double)e4.w;
            }
            {
                #pragma clang fp contract(off)
                float mf = (float)acc;
                float t1 = zn_s + enorm[k];
                float s  = t1 - 2.0f * mf;
                if (s < bv_) { bv_ = s; bi_ = k; }
            }
        }
        #pragma unroll
        for (int o = 32; o >= 1; o >>= 1) {
            float ov = __shfl_xor(bv_, o);
            int   oi = __shfl_xor(bi_, o);
            if (ov < bv_ || (ov == bv_ && oi < bi_)) { bv_ = ov; bi_ = oi; }
        }
        if ((tid & 63) == 0) { wv[tid >> 6] = bv_; wi[tid >> 6] = bi_; }
        __syncthreads();
        if (tid == 0) {
            float fv = wv[0]; int fi = wi[0];
            #pragma unroll
            for (int w = 1; w < 4; ++w)
                if (wv[w] < fv || (wv[w] == fv && wi[w] < fi)) { fv = wv[w]; fi = wi[w]; }
            int old = idx_ws[n];
            kb_s = fi;
            idx_ws[n] = fi;
            idxf_out[n] = (float)fi;
            if (old != fi) enc[(size_t)n * K_CODES + old] = 0.0f;
            enc[(size_t)n * K_CODES + fi] = 1.0f;
        }
        __syncthreads();
        // epilogue: zq + per-row loss
        {
            int kbv = kb_s;
            float e = emb[(size_t)kbv * D_DIM + tid];
            float diff = e - zrow[tid];
            float l = diff * diff;
            zq_out[(size_t)batch * D_DIM * HW + (size_t)tid * HW + p] = e;
            #pragma unroll
            for (int o = 32; o >= 1; o >>= 1) l += __shfl_down(l, o);
            if ((tid & 63) == 0) lw[tid >> 6] = l;
        }
        __syncthreads();
        if (tid == 0) loss_row[n] = (lw[0] + lw[1]) + (lw[2] + lw[3]);
        __syncthreads();
    }
}

// ---------------- K5: codebook counts ----------------
__global__ void k_counts(const int* __restrict__ idx_ws, int* __restrict__ counts) {
    int n = blockIdx.x * 256 + threadIdx.x;
    atomicAdd(&counts[idx_ws[n]], 1);
}

// ---------------- K6: finalize loss + perplexity ----------------
__global__ void k_final(const float* __restrict__ loss_row,
                        const int* __restrict__ counts,
                        float* __restrict__ out_loss, float* __restrict__ out_perp) {
    __shared__ float la[4], pa[4];
    int tid = threadIdx.x;
    float ls = 0.0f, ps = 0.0f;
    for (int i = tid; i < N_ROWS; i += 256) ls += loss_row[i];
    for (int i = tid; i < K_CODES; i += 256) {
        float em = (float)counts[i] * (1.0f / (float)N_ROWS);
        ps += em * logf(em + 1e-10f);
    }
    #pragma unroll
    for (int off = 32; off > 0; off >>= 1) {
        ls += __shfl_down(ls, off);
        ps += __shfl_down(ps, off);
    }
    if ((tid & 63) == 0) { la[tid >> 6] = ls; pa[tid >> 6] = ps; }
    __syncthreads();
    if (tid == 0) {
        float L = (la[0] + la[1] + la[2] + la[3]) * (1.25f / (float)((size_t)N_ROWS * D_DIM));
        float P = expf(-(pa[0] + pa[1] + pa[2] + pa[3]));
        *out_loss = L;
        *out_perp = P;
    }
}

extern "C" void kernel_launch(void* const* d_in, const int* in_sizes, int n_in,
                              void* d_out, int out_size, void* d_ws, size_t ws_size,
                              hipStream_t stream) {
    const float* z   = (const float*)d_in[0];
    const float* emb = (const float*)d_in[1];
    float* out = (float*)d_out;

    // output layout (floats): loss | z_q_out | perplexity | min_encodings | idx
    float* out_loss = out;
    float* out_zq   = out + 1;
    float* out_perp = out + 1 + (size_t)N_ROWS * D_DIM;
    float* out_enc  = out_perp + 1;
    float* out_idxf = out_enc + (size_t)N_ROWS * K_CODES;

    char* ws = (char*)d_ws;
    int*    idx_ws   = (int*)(ws + 0);          // 131072 B
    int*    counts   = (int*)(ws + 131072);     // 4096 B
    float*  enorm    = (float*)(ws + 135168);   // 4096 B
    float*  loss_row = (float*)(ws + 139264);   // 131072 B
    int*    worklist = (int*)(ws + 270336);     // 131072 B
    int*    nflag    = (int*)(ws + 401408);     // 256 B
    ushort* emb_hi   = (ushort*)(ws + 401664);  // 524288 B
    ushort* emb_lo   = (ushort*)(ws + 925952);  // 524288 B

    hipMemsetAsync(counts, 0, K_CODES * sizeof(int), stream);
    hipMemsetAsync(nflag, 0, sizeof(int), stream);
    hipMemsetAsync(out_enc, 0, (size_t)N_ROWS * K_CODES * sizeof(float), stream);

    k_emb_cvt<<<256, 256, 0, stream>>>(emb, emb_hi, emb_lo);
    k_emb_norm<<<(K_CODES + 255) / 256, 256, 0, stream>>>(emb, enorm);
    k_screen_mfma<<<512, 256, 0, stream>>>(z, emb_hi, emb_lo, enorm,
                                           idx_ws, worklist, nflag);
    k_epilogue<<<512, 256, 0, stream>>>(z, emb, idx_ws, out_zq, out_idxf,
                                        out_enc, loss_row);
    k_recheck<<<1024, 256, 0, stream>>>(z, emb, enorm, worklist, nflag, idx_ws,
                                        loss_row, out_zq, out_idxf, out_enc);
    k_counts<<<N_ROWS / 256, 256, 0, stream>>>(idx_ws, counts);
    k_final<<<1, 256, 0, stream>>>(loss_row, counts, out_loss, out_perp);
}

// Round 7
// 410.633 us; speedup vs baseline: 2.1845x; 1.0007x over previous
//
#include <hip/hip_runtime.h>
#include <math.h>

#define K_CODES 1024
#define D_DIM   256
#define HW      1024          // 32*32
#define N_ROWS  32768
#define TAU     2.0e-4f       // ambiguity margin (quantized-score domain)

typedef __attribute__((ext_vector_type(8))) short bf16x8;
typedef __attribute__((ext_vector_type(4))) float f32x4;
#define MFMA16(a, b, c) __builtin_amdgcn_mfma_f32_16x16x32_bf16(a, b, c, 0, 0, 0)

__device__ __forceinline__ unsigned bf16_rne_bits(float x) {
    unsigned u = __float_as_uint(x);
    return (u + 0x7FFFu + ((u >> 16) & 1u)) >> 16;
}

// ---------- numpy-faithful pairwise sum of squares (validated round 2) ----------
__device__ __forceinline__ float pw_block128_sq(const float* a) {
    #pragma clang fp contract(off)
    float S[16];
    #pragma unroll
    for (int l = 0; l < 16; ++l) {
        float x0 = a[l],      x4 = a[64 + l];
        float x1 = a[16 + l], x5 = a[80 + l];
        float x2 = a[32 + l], x6 = a[96 + l];
        float x3 = a[48 + l], x7 = a[112 + l];
        float r0 = x0 * x0 + x4 * x4;
        float r1 = x1 * x1 + x5 * x5;
        float r2 = x2 * x2 + x6 * x6;
        float r3 = x3 * x3 + x7 * x7;
        S[l] = (r0 + r1) + (r2 + r3);
    }
    float u0 = S[0] + S[8],  u1 = S[1] + S[9],  u2 = S[2] + S[10], u3 = S[3] + S[11];
    float u4 = S[4] + S[12], u5 = S[5] + S[13], u6 = S[6] + S[14], u7 = S[7] + S[15];
    float v0 = u0 + u4, v1 = u1 + u5, v2 = u2 + u6, v3 = u3 + u7;
    return (v0 + v2) + (v1 + v3);
}
__device__ __forceinline__ float pw_sum256_sq(const float* a) {
    #pragma clang fp contract(off)
    float b0 = pw_block128_sq(a);
    float b1 = pw_block128_sq(a + 128);
    return b0 + b1;
}

// ---------------- K0: emb -> bf16 hi/lo split ----------------
__global__ void k_emb_cvt(const float* __restrict__ emb,
                          ushort* __restrict__ hi, ushort* __restrict__ lo) {
    int i = blockIdx.x * 256 + threadIdx.x;   // 65536 float4 groups
    float4 v = reinterpret_cast<const float4*>(emb)[i];
    ushort4 h, l;
    float x[4] = {v.x, v.y, v.z, v.w};
    ushort hb[4], lb[4];
    #pragma unroll
    for (int j = 0; j < 4; ++j) {
        unsigned hbits = bf16_rne_bits(x[j]);
        float hf = __uint_as_float(hbits << 16);
        unsigned lbits = bf16_rne_bits(x[j] - hf);
        hb[j] = (ushort)hbits; lb[j] = (ushort)lbits;
    }
    h.x = hb[0]; h.y = hb[1]; h.z = hb[2]; h.w = hb[3];
    l.x = lb[0]; l.y = lb[1]; l.z = lb[2]; l.w = lb[3];
    reinterpret_cast<ushort4*>(hi)[i] = h;
    reinterpret_cast<ushort4*>(lo)[i] = l;
}

// ---------------- K1: emb row norms (numpy-faithful) ----------------
__global__ void k_emb_norm(const float* __restrict__ emb, float* __restrict__ enorm) {
    int k = blockIdx.x * 256 + threadIdx.x;
    if (k < K_CODES) enorm[k] = pw_sum256_sq(emb + (size_t)k * D_DIM);
}

// ---------------- K2: MFMA screen ----------------
// Block: 256 thr (4 waves). 64 rows/block, wave owns 16 rows (A in VGPRs).
// K-loop over 64 tiles of 16 codes; B (hi/lo bf16) double-buffered in LDS.
// Scores s = fl(fl(zn+en) - 2*m); track best1/best2; flag gap<=TAU rows.
#define BT_STR 264              // padded ushort stride (16B-aligned rows)
#define BT_BLK (16 * BT_STR)    // one 16-code half-tile (hi or lo)
__global__ __launch_bounds__(256, 2) void k_screen_mfma(
    const float* __restrict__ z,
    const ushort* __restrict__ emb_hi, const ushort* __restrict__ emb_lo,
    const float* __restrict__ enorm,
    int* __restrict__ idx_ws, int* __restrict__ worklist, int* __restrict__ nflag)
{
    __shared__ __align__(16) float zl[64 * 257];   // 65792 B; reused as B tiles
    __shared__ float enorm_lds[K_CODES];
    __shared__ float zn_sh[64];

    const int tid  = threadIdx.x;
    const int lane = tid & 63, wave = tid >> 6;
    const int blk  = blockIdx.x;                   // 512 blocks
    const int batch = blk >> 4;
    const int p0    = (blk & 15) * 64;
    const float* zb = z + (size_t)batch * D_DIM * HW;

    // stage z tile (f32): zl[p*257 + d] = z[batch][d][p0+p]
    {
        int p = tid & 63;
        for (int d = tid >> 6; d < D_DIM; d += 4)
            zl[p * 257 + d] = zb[(size_t)d * HW + p0 + p];
    }
    // stage enorm
    for (int i = tid; i < K_CODES; i += 256) enorm_lds[i] = enorm[i];
    __syncthreads();

    // numpy-faithful zn per row
    if (tid < 64) zn_sh[tid] = pw_sum256_sq(&zl[tid * 257]);

    // build A fragments in registers (hi/lo bf16), 16 rows per wave
    const int fr = lane & 15, fg = lane >> 4;
    bf16x8 Ah[8], Al[8];
    {
        const float* zr = &zl[(wave * 16 + fr) * 257];
        #pragma unroll
        for (int s = 0; s < 8; ++s) {
            int c0 = s * 32 + fg * 8;
            bf16x8 h, l;
            #pragma unroll
            for (int j = 0; j < 8; ++j) {
                float x = zr[c0 + j];
                unsigned hb = bf16_rne_bits(x);
                float hf = __uint_as_float(hb << 16);
                unsigned lb = bf16_rne_bits(x - hf);
                h[j] = (short)hb; l[j] = (short)lb;
            }
            Ah[s] = h; Al[s] = l;
        }
    }
    __syncthreads();   // zl (f32) dead; B tiles may now overwrite it

    ushort* bt = reinterpret_cast<ushort*>(zl);    // [2 buf][hi,lo][16][BT_STR]

    // stage helper: tile kt -> buffer buf
    auto stage = [&](int buf, int kt) {
        int row = tid >> 5, d16 = tid & 31;
        #pragma unroll
        for (int i = 0; i < 2; ++i) {
            int r = row + 8 * i;
            size_t src = ((size_t)(kt * 16 + r) << 8) + d16 * 8;
            uint4 vh = *reinterpret_cast<const uint4*>(emb_hi + src);
            uint4 vl = *reinterpret_cast<const uint4*>(emb_lo + src);
            *reinterpret_cast<uint4*>(&bt[(buf * 2 + 0) * BT_BLK + r * BT_STR + d16 * 8]) = vh;
            *reinterpret_cast<uint4*>(&bt[(buf * 2 + 1) * BT_BLK + r * BT_STR + d16 * 8]) = vl;
        }
    };

    float zn4[4];
    #pragma unroll
    for (int r = 0; r < 4; ++r) zn4[r] = zn_sh[wave * 16 + fg * 4 + r];

    float b1v[4] = {1e30f, 1e30f, 1e30f, 1e30f};
    float b2v[4] = {1e30f, 1e30f, 1e30f, 1e30f};
    int   b1i[4] = {0, 0, 0, 0};

    stage(0, 0);
    __syncthreads();

    const int boff = fr * BT_STR + fg * 8;
    for (int kt = 0; kt < 64; ++kt) {
        int cur = kt & 1;
        if (kt < 63) stage(cur ^ 1, kt + 1);

        f32x4 aHH = {0.f, 0.f, 0.f, 0.f};
        f32x4 aHM = {0.f, 0.f, 0.f, 0.f};
        f32x4 aLH = {0.f, 0.f, 0.f, 0.f};
        const ushort* bhp = bt + cur * 2 * BT_BLK + boff;
        const ushort* blp = bhp + BT_BLK;
        #pragma unroll
        for (int s = 0; s < 8; ++s) {
            bf16x8 Bh = *reinterpret_cast<const bf16x8*>(bhp + s * 32);
            bf16x8 Bl = *reinterpret_cast<const bf16x8*>(blp + s * 32);
            aHH = MFMA16(Ah[s], Bh, aHH);
            aHM = MFMA16(Ah[s], Bl, aHM);
            aLH = MFMA16(Al[s], Bh, aLH);
        }
        {
            #pragma clang fp contract(off)
            float en = enorm_lds[kt * 16 + fr];
            int kk = kt * 16 + fr;
            #pragma unroll
            for (int r = 0; r < 4; ++r) {
                float m  = aHH[r] + (aHM[r] + aLH[r]);
                float t1 = zn4[r] + en;
                float s  = t1 - 2.0f * m;
                if (s < b1v[r]) { b2v[r] = b1v[r]; b1v[r] = s; b1i[r] = kk; }
                else if (s < b2v[r]) b2v[r] = s;
            }
        }
        __syncthreads();
    }

    // merge best1/best2 across the 16 lanes of each row group
    const int n0w = blk * 64 + wave * 16;
    #pragma unroll
    for (int r = 0; r < 4; ++r) {
        float v1 = b1v[r]; int i1 = b1i[r]; float v2 = b2v[r];
        #pragma unroll
        for (int o = 8; o >= 1; o >>= 1) {
            float ov1 = __shfl_xor(v1, o);
            int   oi1 = __shfl_xor(i1, o);
            float ov2 = __shfl_xor(v2, o);
            bool take = (ov1 < v1) || (ov1 == v1 && oi1 < i1);
            float loser = take ? v1 : ov1;
            if (take) { v1 = ov1; i1 = oi1; }
            v2 = fminf(fminf(v2, ov2), loser);
        }
        if (fr == 0) {
            int n = n0w + fg * 4 + r;
            idx_ws[n] = i1;
            if (v2 - v1 <= TAU) {
                int slot = atomicAdd(nflag, 1);
                worklist[slot] = n;
            }
        }
    }
}

// ---------------- K3: epilogue (zq, loss, idxf, enc ones) ----------------
__global__ __launch_bounds__(256) void k_epilogue(
    const float* __restrict__ z, const float* __restrict__ emb,
    const int* __restrict__ idx_ws,
    float* __restrict__ zq_out, float* __restrict__ idxf_out,
    float* __restrict__ enc, float* __restrict__ loss_row)
{
    __shared__ int kb[64];
    __shared__ float lpart[4][64];
    const int tid = threadIdx.x;
    const int blk = blockIdx.x;                 // 512
    const int batch = blk >> 4;
    const int p0 = (blk & 15) * 64;
    const int n0 = blk * 64;

    if (tid < 64) {
        int k = idx_ws[n0 + tid];
        kb[tid] = k;
        idxf_out[n0 + tid] = (float)k;
        enc[(size_t)(n0 + tid) * K_CODES + k] = 1.0f;
    }
    __syncthreads();

    int p = tid & 63, dg = tid >> 6;
    const float* zp = z + (size_t)batch * D_DIM * HW + p0 + p;
    float* zqp = zq_out + (size_t)batch * D_DIM * HW + p0 + p;
    const float* er = emb + (size_t)kb[p] * D_DIM;
    float ls = 0.0f;
    for (int d = dg * 64; d < dg * 64 + 64; ++d) {
        float e = er[d];
        float zv = zp[(size_t)d * HW];
        float df = e - zv;
        ls += df * df;
        zqp[(size_t)d * HW] = e;
    }
    lpart[dg][p] = ls;
    __syncthreads();
    if (tid < 64)
        loss_row[n0 + tid] = (lpart[0][tid] + lpart[1][tid]) + (lpart[2][tid] + lpart[3][tid]);
}

// ---------------- K4: exact f64 recheck for flagged rows (validated) ----------------
__global__ __launch_bounds__(256) void k_recheck(
    const float* __restrict__ z, const float* __restrict__ emb,
    const float* __restrict__ enorm,
    const int* __restrict__ worklist, const int* __restrict__ nflag,
    int* __restrict__ idx_ws, float* __restrict__ loss_row,
    float* __restrict__ zq_out, float* __restrict__ idxf_out,
    float* __restrict__ enc)
{
    __shared__ __align__(16) float zrow[D_DIM];
    __shared__ float zn_s;
    __shared__ float wv[4]; __shared__ int wi[4];
    __shared__ int kb_s;
    __shared__ float lw[4];

    const int tid = threadIdx.x;
    const int nf = *nflag;
    for (int j = blockIdx.x; j < nf; j += gridDim.x) {
        int n = worklist[j];
        int batch = n >> 10, p = n & (HW - 1);
        zrow[tid] = z[(size_t)batch * D_DIM * HW + (size_t)tid * HW + p];
        __syncthreads();
        if (tid == 0) zn_s = pw_sum256_sq(zrow);
        __syncthreads();

        float bv_ = 1e30f; int bi_ = 0;
        #pragma unroll
        for (int c = 0; c < 4; ++c) {
            int k = tid * 4 + c;
            const float* ek = emb + (size_t)k * D_DIM;
            double acc = 0.0;
            #pragma unroll 4
            for (int d = 0; d < D_DIM; d += 4) {
                float4 e4 = *reinterpret_cast<const float4*>(ek + d);
                float4 z4 = *reinterpret_cast<const float4*>(&zrow[d]);
                acc += (double)z4.x * (double)e4.x + (double)z4.y * (double)e4.y
                     + (double)z4.z * (double)e4.z + (double)z4.w * (double)e4.w;
            }
            {
                #pragma clang fp contract(off)
                float mf = (float)acc;
                float t1 = zn_s + enorm[k];
                float s  = t1 - 2.0f * mf;
                if (s < bv_) { bv_ = s; bi_ = k; }
            }
        }
        #pragma unroll
        for (int o = 32; o >= 1; o >>= 1) {
            float ov = __shfl_xor(bv_, o);
            int   oi = __shfl_xor(bi_, o);
            if (ov < bv_ || (ov == bv_ && oi < bi_)) { bv_ = ov; bi_ = oi; }
        }
        if ((tid & 63) == 0) { wv[tid >> 6] = bv_; wi[tid >> 6] = bi_; }
        __syncthreads();
        if (tid == 0) {
            float fv = wv[0]; int fi = wi[0];
            #pragma unroll
            for (int w = 1; w < 4; ++w)
                if (wv[w] < fv || (wv[w] == fv && wi[w] < fi)) { fv = wv[w]; fi = wi[w]; }
            int old = idx_ws[n];
            kb_s = fi;
            idx_ws[n] = fi;
            idxf_out[n] = (float)fi;
            if (old != fi) enc[(size_t)n * K_CODES + old] = 0.0f;
            enc[(size_t)n * K_CODES + fi] = 1.0f;
        }
        __syncthreads();
        // epilogue: zq + per-row loss
        {
            int kbv = kb_s;
            float e = emb[(size_t)kbv * D_DIM + tid];
            float diff = e - zrow[tid];
            float l = diff * diff;
            zq_out[(size_t)batch * D_DIM * HW + (size_t)tid * HW + p] = e;
            #pragma unroll
            for (int o = 32; o >= 1; o >>= 1) l += __shfl_down(l, o);
            if ((tid & 63) == 0) lw[tid >> 6] = l;
        }
        __syncthreads();
        if (tid == 0) loss_row[n] = (lw[0] + lw[1]) + (lw[2] + lw[3]);
        __syncthreads();
    }
}

// ---------------- K5: codebook counts ----------------
__global__ void k_counts(const int* __restrict__ idx_ws, int* __restrict__ counts) {
    int n = blockIdx.x * 256 + threadIdx.x;
    atomicAdd(&counts[idx_ws[n]], 1);
}

// ---------------- K6: finalize loss + perplexity ----------------
__global__ void k_final(const float* __restrict__ loss_row,
                        const int* __restrict__ counts,
                        float* __restrict__ out_loss, float* __restrict__ out_perp) {
    __shared__ float la[4], pa[4];
    int tid = threadIdx.x;
    float ls = 0.0f, ps = 0.0f;
    for (int i = tid; i < N_ROWS; i += 256) ls += loss_row[i];
    for (int i = tid; i < K_CODES; i += 256) {
        float em = (float)counts[i] * (1.0f / (float)N_ROWS);
        ps += em * logf(em + 1e-10f);
    }
    #pragma unroll
    for (int off = 32; off > 0; off >>= 1) {
        ls += __shfl_down(ls, off);
        ps += __shfl_down(ps, off);
    }
    if ((tid & 63) == 0) { la[tid >> 6] = ls; pa[tid >> 6] = ps; }
    __syncthreads();
    if (tid == 0) {
        float L = (la[0] + la[1] + la[2] + la[3]) * (1.25f / (float)((size_t)N_ROWS * D_DIM));
        float P = expf(-(pa[0] + pa[1] + pa[2] + pa[3]));
        *out_loss = L;
        *out_perp = P;
    }
}

extern "C" void kernel_launch(void* const* d_in, const int* in_sizes, int n_in,
                              void* d_out, int out_size, void* d_ws, size_t ws_size,
                              hipStream_t stream) {
    const float* z   = (const float*)d_in[0];
    const float* emb = (const float*)d_in[1];
    float* out = (float*)d_out;

    // output layout (floats): loss | z_q_out | perplexity | min_encodings | idx
    float* out_loss = out;
    float* out_zq   = out + 1;
    float* out_perp = out + 1 + (size_t)N_ROWS * D_DIM;
    float* out_enc  = out_perp + 1;
    float* out_idxf = out_enc + (size_t)N_ROWS * K_CODES;

    char* ws = (char*)d_ws;
    int*    idx_ws   = (int*)(ws + 0);          // 131072 B
    int*    counts   = (int*)(ws + 131072);     // 4096 B
    float*  enorm    = (float*)(ws + 135168);   // 4096 B
    float*  loss_row = (float*)(ws + 139264);   // 131072 B
    int*    worklist = (int*)(ws + 270336);     // 131072 B
    int*    nflag    = (int*)(ws + 401408);     // 256 B
    ushort* emb_hi   = (ushort*)(ws + 401664);  // 524288 B
    ushort* emb_lo   = (ushort*)(ws + 925952);  // 524288 B

    hipMemsetAsync(counts, 0, K_CODES * sizeof(int), stream);
    hipMemsetAsync(nflag, 0, sizeof(int), stream);
    hipMemsetAsync(out_enc, 0, (size_t)N_ROWS * K_CODES * sizeof(float), stream);

    k_emb_cvt<<<256, 256, 0, stream>>>(emb, emb_hi, emb_lo);
    k_emb_norm<<<(K_CODES + 255) / 256, 256, 0, stream>>>(emb, enorm);
    k_screen_mfma<<<512, 256, 0, stream>>>(z, emb_hi, emb_lo, enorm,
                                           idx_ws, worklist, nflag);
    k_epilogue<<<512, 256, 0, stream>>>(z, emb, idx_ws, out_zq, out_idxf,
                                        out_enc, loss_row);
    k_recheck<<<1024, 256, 0, stream>>>(z, emb, enorm, worklist, nflag, idx_ws,
                                        loss_row, out_zq, out_idxf, out_enc);
    k_counts<<<N_ROWS / 256, 256, 0, stream>>>(idx_ws, counts);
    k_final<<<1, 256, 0, stream>>>(loss_row, counts, out_loss, out_perp);
}